// Round 13
// baseline (256.726 us; speedup 1.0000x reference)
//
#include <hip/hip_runtime.h>
#include <hip/hip_bf16.h>
#include <math.h>

#define NN 4096      // nodes
#define NE 16384     // edges
#define FIN 64
#define FE 16
#define HIDD 128
#define OUTD 64
#define NG 32
#define EP (NE + NN) // edges + self loops
#define KSPLIT 2
#define NCH (64 / KSPLIT)  // 32 chunks per z-block

typedef __attribute__((ext_vector_type(4))) unsigned u4v;
typedef __attribute__((ext_vector_type(4))) float f4v;
typedef _Float16 f16x8 __attribute__((ext_vector_type(8)));

union FragH { u4v u; f16x8 h; };
union FH2 { _Float16 f[2]; unsigned u; };
union F16x8U { _Float16 f[8]; u4v u; };

// ================= prep: edge MLP (f16 out) | bias | dst-hist | splitB =========
#define PB_EMLP  4096
#define PB_BIAS  (PB_EMLP + 4096)
#define PB_HIST  (PB_BIAS + 32)
#define PB_TOTAL (PB_HIST + 64)

__global__ void k_prep(const float* __restrict__ ea0, const float* __restrict__ ea1,
                       const float* __restrict__ w1, const float* __restrict__ b1,
                       const float* __restrict__ w2, const float* __restrict__ b2,
                       const float* __restrict__ w3,
                       const float* __restrict__ X0, const float* __restrict__ X1,
                       const float* __restrict__ b3,
                       const int* __restrict__ ei0, const int* __restrict__ ei1,
                       unsigned short* __restrict__ B1t,
                       _Float16* __restrict__ h0, _Float16* __restrict__ h1g,
                       float* __restrict__ Bb0, float* __restrict__ Bb1,
                       int* __restrict__ rowcnt) {
    int b = blockIdx.x, t = threadIdx.x; // 256
    if (b < PB_EMLP) {
        int gi = b >> 11;
        int e0 = (b & 2047) * 8;
        const float* ea = gi ? ea1 : ea0;
        _Float16* hout = gi ? h1g : h0;
        __shared__ float h1s[8][HIDD];
#pragma unroll
        for (int r = 0; r < 4; ++r) {
            int idx = r * 256 + t;
            int e1 = idx >> 7, j = idx & 127;
            float acc = b1[j];
#pragma unroll
            for (int i = 0; i < FE; ++i) acc += ea[(e0 + e1) * FE + i] * w1[i * HIDD + j];
            h1s[e1][j] = fmaxf(acc, 0.f);
        }
        __syncthreads();
#pragma unroll
        for (int r = 0; r < 2; ++r) {
            int idx = r * 256 + t;
            int e1 = idx >> 6, j = idx & 63;
            float acc = b2[j];
#pragma unroll 16
            for (int k = 0; k < HIDD; ++k) acc += h1s[e1][k] * w2[k * 64 + j];
            hout[(size_t)(e0 + e1) * 64 + j] = (_Float16)fmaxf(acc, 0.f);
        }
    } else if (b < PB_BIAS) {
        int bb = b - PB_EMLP;         // 0..4095
        int gi = bb >> 11;
        int n = (bb & 2047) * 2 + (t >> 7);
        int o = t & 127;
        const float* X = gi ? X1 : X0;
        float* Bb = gi ? Bb1 : Bb0;
        float acc = 0.f;
#pragma unroll 16
        for (int i = 0; i < FIN; ++i) acc += X[n * FIN + i] * b3[i * HIDD + o];
        Bb[(size_t)n * HIDD + o] = acc;
    } else if (b < PB_HIST) {
        int tid = (b - PB_BIAS) * 256 + t; // 0..8191
        for (int idx = tid; idx < 2 * EP; idx += 32 * 256) {
            int gi = idx / EP, e = idx % EP;
            const int* dst = (gi ? ei1 : ei0) + NE;
            int d = (e < NE) ? dst[e] : e - NE;
            atomicAdd(&rowcnt[gi * NN + d], 1);
        }
    } else {
        // splitB: w3[c][i][o] -> f16 image B1t[c][o][i]
        __shared__ float lds[64 * 129];
        int c = b - PB_HIST;
#pragma unroll
        for (int r = 0; r < 32; ++r) {
            int idx = r * 256 + t;       // i = idx>>7, o = idx&127
            lds[(idx >> 7) * 129 + (idx & 127)] = w3[(size_t)c * 8192 + idx];
        }
        __syncthreads();
#pragma unroll
        for (int r = 0; r < 32; ++r) {
            int e = r * 256 + t;         // o = e>>6, i = e&63
            float v = lds[(e & 63) * 129 + (e >> 6)];
            union { _Float16 f; unsigned short u; } cv;
            cv.f = (_Float16)v;          // RNE
            B1t[(size_t)c * 8192 + e] = cv.u;
        }
    }
}

// ================= scan: rowptr per graph (shfl scan) + batch ranges =========
__global__ void k_scan(const int* __restrict__ rowcnt, int* __restrict__ rowptr,
                       const int* __restrict__ batch0, const int* __restrict__ batch1,
                       int* __restrict__ br) {
    int b = blockIdx.x;
    if (b < 2) {
        int gi = b;
        const int* cnt = rowcnt + gi * NN;
        int* rp = rowptr + gi * (NN + 1);
        int t = threadIdx.x; // 1024
        int lane = t & 63, w = t >> 6; // 16 waves
        int base = t * 4;
        int v0 = cnt[base], v1 = cnt[base + 1], v2 = cnt[base + 2], v3 = cnt[base + 3];
        int s = v0 + v1 + v2 + v3;
        int inc = s;
#pragma unroll
        for (int off = 1; off < 64; off <<= 1) {
            int u = __shfl_up(inc, off);
            if (lane >= off) inc += u;
        }
        __shared__ int wsum[16];
        if (lane == 63) wsum[w] = inc;
        __syncthreads();
        if (t < 16) {
            int ws = wsum[t];
            int wi = ws;
#pragma unroll
            for (int off = 1; off < 16; off <<= 1) {
                int u = __shfl_up(wi, off);
                if (t >= off) wi += u;
            }
            wsum[t] = wi - ws; // exclusive wave offset
        }
        __syncthreads();
        int run = wsum[w] + inc - s;
        rp[base] = run; run += v0;
        rp[base + 1] = run; run += v1;
        rp[base + 2] = run; run += v2;
        rp[base + 3] = run; run += v3;
        if (t == 1023) rp[NN] = run;
    } else {
        int t = threadIdx.x;
        if (t < 66) {
            int gi = t / 33, g = t % 33;
            const int* batch = gi ? batch1 : batch0;
            int lo = 0, hi = NN;
            while (lo < hi) {
                int mid = (lo + hi) >> 1;
                if (batch[mid] < g) lo = mid + 1; else hi = mid;
            }
            br[gi * 33 + g] = lo;
        }
    }
}

// ================= fill CSR adjacency =================
__global__ void k_fill(const int* __restrict__ ei0, const int* __restrict__ ei1,
                       const int* __restrict__ rowptr, int* __restrict__ cnt2,
                       int* __restrict__ adj) {
    int idx = blockIdx.x * 256 + threadIdx.x;
    if (idx >= 2 * EP) return;
    int gi = idx / EP, e = idx % EP;
    const int* dst = (gi ? ei1 : ei0) + NE;
    int d = (e < NE) ? dst[e] : e - NE;
    int pos = rowptr[gi * (NN + 1) + d] + atomicAdd(&cnt2[gi * NN + d], 1);
    adj[gi * EP + pos] = e;
}

// ===== NNConv message GEMM: barrier-free, B from L2, slim 64x32 wave tile =====
// block = 64 edges x 64 cols (2 waves x 32 cols); grid y = colblock(2) x z-half(2)
__global__ void __launch_bounds__(128, 3)
k_nnconv(const float* __restrict__ x0, const float* __restrict__ x1,
         const _Float16* __restrict__ h_0, const _Float16* __restrict__ h_1,
         const unsigned short* __restrict__ B1t,
         const float* __restrict__ Bb0, const float* __restrict__ Bb1,
         const int* __restrict__ ei0, const int* __restrict__ ei1,
         _Float16* __restrict__ msgh) {
    __shared__ __align__(16) float sm[64 * 68]; // 17.4 KB epilogue bounce (pad 68)
    int gi = blockIdx.z;
    const float* x = gi ? x1 : x0;
    const _Float16* hh = gi ? h_1 : h_0;
    const float* Bb = gi ? Bb1 : Bb0;
    const int* src = gi ? ei1 : ei0;

    int t = threadIdx.x;       // 128
    int e0 = blockIdx.x * 64;
    int cb = blockIdx.y & 1;   // col block: cols cb*64 .. +63
    int z = blockIdx.y >> 1;   // K-split half
    int wv = t >> 6;           // col half within block (32 cols)
    int l = t & 63, q4 = l >> 4, c16 = l & 15;

    // ---- prologue: x rows -> f16 fragments; h base offsets ----
    FragH xf[4][2];
    int hb_[4];
#pragma unroll
    for (int mf = 0; mf < 4; ++mf) {
        int s_ = src[e0 + mf * 16 + c16];
        hb_[mf] = (e0 + mf * 16 + c16) * 64 + z * NCH;
        const float* xr = &x[(size_t)s_ * FIN];
#pragma unroll
        for (int kf = 0; kf < 2; ++kf) {
            float xv[8];
            *(float4*)&xv[0] = *(const float4*)&xr[kf * 32 + q4 * 8];
            *(float4*)&xv[4] = *(const float4*)&xr[kf * 32 + q4 * 8 + 4];
            u4v w;
#pragma unroll
            for (int p = 0; p < 4; ++p) {
                FH2 c2;
                c2.f[0] = (_Float16)xv[2 * p];
                c2.f[1] = (_Float16)xv[2 * p + 1];
                w[p] = c2.u;
            }
            xf[mf][kf].u = w;
        }
    }

    f4v acc[4][2];
#pragma unroll
    for (int a = 0; a < 4; ++a)
#pragma unroll
        for (int b = 0; b < 2; ++b) acc[a][b] = (f4v){0.f, 0.f, 0.f, 0.f};

    const u4v* bp = (const u4v*)B1t; // chunk = 1024 u4v of [o][i] f16

#define LOADF(buf, cg)                                                          \
    {                                                                           \
        const u4v* cp = bp + (size_t)(cg) * 1024;                               \
        _Pragma("unroll") for (int kf = 0; kf < 2; ++kf)                        \
        _Pragma("unroll") for (int nf = 0; nf < 2; ++nf)                        \
            buf[kf * 2 + nf].u =                                                \
                cp[(cb * 64 + wv * 32 + nf * 16 + c16) * 8 + kf * 4 + q4];      \
    }

#define DOMFMA(buf, COMP)                                                       \
    {                                                                           \
        _Pragma("unroll") for (int mf = 0; mf < 4; ++mf) {                      \
            unsigned hw = hs[mf].COMP;                                          \
            hw |= hw << 16;                                                     \
            FragH hb; hb.u = (u4v){hw, hw, hw, hw};                             \
            _Pragma("unroll") for (int kf = 0; kf < 2; ++kf) {                  \
                FragH a1;                                                       \
                a1.h = hb.h * xf[mf][kf].h;                                     \
                _Pragma("unroll") for (int nf = 0; nf < 2; ++nf)                \
                    acc[mf][nf] = __builtin_amdgcn_mfma_f32_16x16x32_f16(       \
                        a1.h, buf[kf * 2 + nf].h, acc[mf][nf], 0, 0, 0);        \
            }                                                                   \
        }                                                                       \
    }

    FragH bA[4], bB[4];
    ushort4 hs[4];
    LOADF(bA, z * NCH);
#pragma unroll 1
    for (int cl = 0; cl < NCH; cl += 4) {
#pragma unroll
        for (int mf = 0; mf < 4; ++mf)
            hs[mf] = *(const ushort4*)&hh[hb_[mf] + cl];
        LOADF(bB, z * NCH + cl + 1);
        DOMFMA(bA, x);
        LOADF(bA, z * NCH + cl + 2);
        DOMFMA(bB, y);
        LOADF(bB, z * NCH + cl + 3);
        DOMFMA(bA, z);
        if (cl + 4 < NCH) LOADF(bA, z * NCH + cl + 4);
        DOMFMA(bB, w);
    }
#undef LOADF
#undef DOMFMA

    // epilogue: bounce acc through padded LDS, f16 16B stores (64 rows x 64 cols)
    _Float16* mb = msgh + (size_t)(gi * KSPLIT + z) * NE * HIDD;
    int z0 = (z == 0);
#pragma unroll
    for (int mf = 0; mf < 4; ++mf)
#pragma unroll
        for (int j = 0; j < 4; ++j) {
            int rr = mf * 16 + q4 * 4 + j;
            int col = wv * 32 + c16;
            sm[rr * 68 + col] = acc[mf][0][j];
            sm[rr * 68 + col + 16] = acc[mf][1][j];
        }
    __syncthreads();
#pragma unroll
    for (int it = 0; it < 4; ++it) {
        int u = it * 128 + t;       // 0..511 units of 8 f16
        int row = u >> 3, c8 = u & 7;
        int eg = e0 + row;
        float v[8];
        *(float4*)&v[0] = *(float4*)&sm[row * 68 + c8 * 8];
        *(float4*)&v[4] = *(float4*)&sm[row * 68 + c8 * 8 + 4];
        if (z0) {
            int s_ = src[eg];
            const float* bbr = &Bb[(size_t)s_ * HIDD + cb * 64 + c8 * 8];
#pragma unroll
            for (int j = 0; j < 8; ++j) v[j] += bbr[j];
        }
        F16x8U cv;
#pragma unroll
        for (int j = 0; j < 8; ++j) cv.f[j] = (_Float16)v[j];
        *(u4v*)&mb[(size_t)eg * HIDD + cb * 64 + c8 * 8] = cv.u;
    }
}

// ===== h1 = relu(gather(msg) + x@root_w + cb); hp = h1@gat_w; a_s,a_d =====
__global__ void k_h1hp(const _Float16* __restrict__ msgh,
                       const int* __restrict__ rowptr, const int* __restrict__ adj,
                       const float* __restrict__ X0, const float* __restrict__ X1,
                       const float* __restrict__ rw, const float* __restrict__ cb,
                       const float* __restrict__ gw,
                       const float* __restrict__ asw, const float* __restrict__ adw,
                       float* __restrict__ hp0, float* __restrict__ hp1,
                       float* __restrict__ a_s0, float* __restrict__ a_s1,
                       float* __restrict__ a_d0, float* __restrict__ a_d1) {
    int gi = blockIdx.y;
    const float* X = gi ? X1 : X0;
    float* hp = gi ? hp1 : hp0;
    float* a_s = gi ? a_s1 : a_s0;
    float* a_d = gi ? a_d1 : a_d0;
    const int* rp = rowptr + gi * (NN + 1);
    const int* aj = adj + gi * EP;
    const _Float16* m0 = msgh + (size_t)(gi * KSPLIT + 0) * NE * HIDD;
    const _Float16* m1 = msgh + (size_t)(gi * KSPLIT + 1) * NE * HIDD;
    int n0 = blockIdx.x * 16;
    int t = threadIdx.x;        // 512
    int o = t & 127, q = t >> 7;
    __shared__ float xsh[16][FIN];
    __shared__ float h1s[16][HIDD];
    __shared__ float s1[16][2], s2[16][2];
#pragma unroll
    for (int r = 0; r < 2; ++r) {
        int idx = r * 512 + t;
        xsh[idx >> 6][idx & 63] = X[(n0 + (idx >> 6)) * FIN + (idx & 63)];
    }
    __syncthreads();
    float accs[4];
#pragma unroll
    for (int nn = 0; nn < 4; ++nn) {
        int n = n0 + q * 4 + nn;
        float acc = cb[o];
        int lo = rp[n], hi = rp[n + 1];
        for (int p = lo; p < hi; ++p) {
            int e = aj[p];
            if (e < NE) {
                size_t eo = (size_t)e * HIDD + o;
                acc += (float)m0[eo] + (float)m1[eo];
            }
        }
        accs[nn] = acc;
    }
#pragma unroll 8
    for (int i = 0; i < FIN; ++i) {
        float w = rw[i * HIDD + o];
#pragma unroll
        for (int nn = 0; nn < 4; ++nn) accs[nn] += xsh[q * 4 + nn][i] * w;
    }
#pragma unroll
    for (int nn = 0; nn < 4; ++nn) h1s[q * 4 + nn][o] = fmaxf(accs[nn], 0.f);
    __syncthreads();
#pragma unroll
    for (int nn = 0; nn < 4; ++nn) accs[nn] = 0.f;
#pragma unroll 8
    for (int k = 0; k < HIDD; ++k) {
        float w = gw[k * HIDD + o];
#pragma unroll
        for (int nn = 0; nn < 4; ++nn) accs[nn] += h1s[q * 4 + nn][k] * w;
    }
#pragma unroll
    for (int nn = 0; nn < 4; ++nn) {
        int n = n0 + q * 4 + nn;
        hp[(size_t)n * HIDD + o] = accs[nn];
        float p1 = accs[nn] * asw[o], p2 = accs[nn] * adw[o];
#pragma unroll
        for (int off = 32; off; off >>= 1) {
            p1 += __shfl_down(p1, off);
            p2 += __shfl_down(p2, off);
        }
        if ((o & 63) == 0) { s1[q * 4 + nn][o >> 6] = p1; s2[q * 4 + nn][o >> 6] = p2; }
    }
    __syncthreads();
    if (t < 16) {
        a_s[n0 + t] = s1[t][0] + s1[t][1];
        a_d[n0 + t] = s2[t][0] + s2[t][1];
    }
}

// ===== GAT: wave per dst node =====
__global__ void k_gat(const int* __restrict__ rowptr, const int* __restrict__ adj,
                      const int* __restrict__ ei0, const int* __restrict__ ei1,
                      const float* __restrict__ hp0, const float* __restrict__ hp1,
                      const float* __restrict__ as0, const float* __restrict__ as1,
                      const float* __restrict__ ad0, const float* __restrict__ ad1,
                      const float* __restrict__ gb,
                      float* __restrict__ h2_0, float* __restrict__ h2_1) {
    int gi = blockIdx.y;
    const int* src = gi ? ei1 : ei0;
    const float* hp = gi ? hp1 : hp0;
    const float* a_s = gi ? as1 : as0;
    const float* a_d = gi ? ad1 : ad0;
    float* h2 = gi ? h2_1 : h2_0;
    const int* rp = rowptr + gi * (NN + 1);
    const int* aj = adj + gi * EP;
    int w = threadIdx.x >> 6, l = threadIdx.x & 63;
    int n = blockIdx.x * 4 + w;
    int lo = rp[n], deg = rp[n + 1] - lo;
    float adn = a_d[n];
    float m = -1e30f;
    for (int base = 0; base < deg; base += 64) {
        float sc = -1e30f;
        int j = base + l;
        if (j < deg) {
            int e = aj[lo + j];
            int si = (e < NE) ? src[e] : n;
            float xsc = a_s[si] + adn;
            sc = xsc > 0.f ? xsc : 0.2f * xsc;
        }
#pragma unroll
        for (int off = 32; off; off >>= 1) sc = fmaxf(sc, __shfl_xor(sc, off));
        m = fmaxf(m, sc);
    }
    float den = 0.f;
    for (int base = 0; base < deg; base += 64) {
        float ev = 0.f;
        int j = base + l;
        if (j < deg) {
            int e = aj[lo + j];
            int si = (e < NE) ? src[e] : n;
            float xsc = a_s[si] + adn;
            float sc = xsc > 0.f ? xsc : 0.2f * xsc;
            ev = expf(sc - m);
        }
#pragma unroll
        for (int off = 32; off; off >>= 1) ev += __shfl_xor(ev, off);
        den += ev;
    }
    float inv = 1.f / (den + 1e-16f);
    float acc0 = 0.f, acc1 = 0.f;
    for (int j = 0; j < deg; ++j) {
        int e = aj[lo + j];
        int si = (e < NE) ? src[e] : n;
        float xsc = a_s[si] + adn;
        float sc = xsc > 0.f ? xsc : 0.2f * xsc;
        float al = expf(sc - m) * inv;
        acc0 += al * hp[(size_t)si * HIDD + l];
        acc1 += al * hp[(size_t)si * HIDD + 64 + l];
    }
    h2[(size_t)n * HIDD + l] = fmaxf(acc0 + gb[l], 0.f);
    h2[(size_t)n * HIDD + 64 + l] = fmaxf(acc1 + gb[64 + l], 0.f);
}

// ===== mean-pool (batch ranges) + fc1 =====
__global__ void k_poolfc1(const float* __restrict__ h2_0, const float* __restrict__ h2_1,
                          const int* __restrict__ br,
                          const float* __restrict__ w, const float* __restrict__ bias,
                          float* __restrict__ z) {
    int gi = blockIdx.x >> 5, g = blockIdx.x & 31;
    const float* h2 = gi ? h2_1 : h2_0;
    int lo = br[gi * 33 + g], hi = br[gi * 33 + g + 1];
    int t = threadIdx.x; // 128
    __shared__ float pool[HIDD];
    float acc = 0.f;
    for (int n = lo; n < hi; ++n) acc += h2[(size_t)n * HIDD + t];
    pool[t] = acc;
    __syncthreads();
    if (t < 64) {
        float c = fmaxf((float)(hi - lo), 1.f);
        float a = bias[t];
#pragma unroll 16
        for (int o = 0; o < HIDD; ++o) a += (pool[o] / c) * w[o * OUTD + t];
        z[gi * NG * OUTD + g * OUTD + t] = fmaxf(a, 0.f);
    }
}

// ===== final =====
__global__ void k_final(const float* __restrict__ zz,
                        const float* __restrict__ w, const float* __restrict__ b,
                        float* __restrict__ out) {
    int g = threadIdx.x; // 32
    const float* z1 = zz;
    const float* z2 = zz + NG * OUTD;
    float acc = b[0];
#pragma unroll
    for (int j = 0; j < OUTD; ++j) acc += fabsf(z1[g * OUTD + j] - z2[g * OUTD + j]) * w[j];
    out[g] = 1.f / (1.f + expf(-acc));
}

extern "C" void kernel_launch(void* const* d_in, const int* in_sizes, int n_in,
                              void* d_out, int out_size, void* d_ws, size_t ws_size,
                              hipStream_t stream) {
    const float* x0     = (const float*)d_in[0];
    const int*   ei0    = (const int*)d_in[1];
    const float* ea0    = (const float*)d_in[2];
    const int*   b0     = (const int*)d_in[3];
    const float* x1     = (const float*)d_in[4];
    const int*   ei1    = (const int*)d_in[5];
    const float* ea1    = (const float*)d_in[6];
    const int*   b1     = (const int*)d_in[7];
    const float* e_w1 = (const float*)d_in[8];
    const float* e_b1 = (const float*)d_in[9];
    const float* e_w2 = (const float*)d_in[10];
    const float* e_b2 = (const float*)d_in[11];
    const float* e_w3 = (const float*)d_in[12];
    const float* e_b3 = (const float*)d_in[13];
    const float* root_w = (const float*)d_in[14];
    const float* conv1_b = (const float*)d_in[15];
    const float* gat_w = (const float*)d_in[16];
    const float* att_src = (const float*)d_in[17];
    const float* att_dst = (const float*)d_in[18];
    const float* gat_b = (const float*)d_in[19];
    const float* fc1_w = (const float*)d_in[20];
    const float* fc1_b = (const float*)d_in[21];
    const float* fc2_w = (const float*)d_in[22];
    const float* fc2_b = (const float*)d_in[23];

    float* ws = (float*)d_ws;
    size_t off = 0;
    auto alloc = [&](size_t n) { float* p = ws + off; off += n; return p; };
    // int region (zeroed part first)
    int* rowcnt = (int*)alloc(2 * NN);
    int* cnt2   = (int*)alloc(2 * NN);
    size_t zero_elems = off;
    int* rowptr = (int*)alloc(2 * (NN + 1));
    int* br     = (int*)alloc(66);
    int* adj    = (int*)alloc(2 * EP);
    // float scratch
    _Float16* h[2] = {(_Float16*)alloc((size_t)NE * 64 / 2),
                      (_Float16*)alloc((size_t)NE * 64 / 2)};       // f16 h
    unsigned short* B1t = (unsigned short*)alloc((size_t)4096 * 128 / 2); // 1MB f16 image
    float* Bb[2]  = {alloc((size_t)NN * HIDD), alloc((size_t)NN * HIDD)};
    _Float16* msgh = (_Float16*)alloc((size_t)2 * KSPLIT * NE * HIDD / 2); // 16.7MB f16
    float* hp[2]  = {alloc((size_t)NN * HIDD), alloc((size_t)NN * HIDD)};
    float* a_s[2] = {alloc(NN), alloc(NN)};
    float* a_d[2] = {alloc(NN), alloc(NN)};
    float* h2[2]  = {alloc((size_t)NN * HIDD), alloc((size_t)NN * HIDD)};
    float* zz     = alloc((size_t)2 * NG * OUTD);

    (void)hipMemsetAsync(ws, 0, zero_elems * 4, stream);
    k_prep<<<PB_TOTAL, 256, 0, stream>>>(ea0, ea1, e_w1, e_b1, e_w2, e_b2, e_w3,
                                         x0, x1, e_b3, ei0, ei1,
                                         B1t, h[0], h[1], Bb[0], Bb[1],
                                         rowcnt);
    k_scan<<<3, 1024, 0, stream>>>(rowcnt, rowptr, b0, b1, br);
    k_fill<<<(2 * EP + 255) / 256, 256, 0, stream>>>(ei0, ei1, rowptr, cnt2, adj);
    k_nnconv<<<dim3(NE / 64, 2 * KSPLIT, 2), 128, 0, stream>>>(
        x0, x1, h[0], h[1], B1t, Bb[0], Bb[1], ei0, ei1, msgh);
    k_h1hp<<<dim3(NN / 16, 2), 512, 0, stream>>>(
        msgh, rowptr, adj, x0, x1, root_w, conv1_b, gat_w, att_src, att_dst,
        hp[0], hp[1], a_s[0], a_s[1], a_d[0], a_d[1]);
    k_gat<<<dim3(NN / 4, 2), 256, 0, stream>>>(
        rowptr, adj, ei0, ei1, hp[0], hp[1], a_s[0], a_s[1], a_d[0], a_d[1],
        gat_b, h2[0], h2[1]);
    k_poolfc1<<<64, HIDD, 0, stream>>>(h2[0], h2[1], br, fc1_w, fc1_b, zz);
    k_final<<<1, NG, 0, stream>>>(zz, fc2_w, fc2_b, (float*)d_out);
}

// Round 14
// 239.470 us; speedup vs baseline: 1.0721x; 1.0721x over previous
//
#include <hip/hip_runtime.h>
#include <hip/hip_bf16.h>
#include <math.h>

#define NN 4096      // nodes
#define NE 16384     // edges
#define FIN 64
#define FE 16
#define HIDD 128
#define OUTD 64
#define NG 32
#define EP (NE + NN) // edges + self loops
#define KSPLIT 2
#define NCH (64 / KSPLIT)  // 32 chunks per z-block

typedef __attribute__((ext_vector_type(4))) unsigned u4v;
typedef __attribute__((ext_vector_type(4))) float f4v;
typedef _Float16 f16x8 __attribute__((ext_vector_type(8)));

union FragH { u4v u; f16x8 h; };
union FH2 { _Float16 f[2]; unsigned u; };
union F16x8U { _Float16 f[8]; u4v u; };

// ================= prep: edge MLP | bias | dst-hist | splitB =========
#define PB_EMLP  4096
#define PB_BIAS  (PB_EMLP + 4096)
#define PB_HIST  (PB_BIAS + 32)
#define PB_TOTAL (PB_HIST + 64)

__global__ void k_prep(const float* __restrict__ ea0, const float* __restrict__ ea1,
                       const float* __restrict__ w1, const float* __restrict__ b1,
                       const float* __restrict__ w2, const float* __restrict__ b2,
                       const float* __restrict__ w3,
                       const float* __restrict__ X0, const float* __restrict__ X1,
                       const float* __restrict__ b3,
                       const int* __restrict__ ei0, const int* __restrict__ ei1,
                       unsigned short* __restrict__ B1t,
                       float* __restrict__ h0, float* __restrict__ h1g,
                       float* __restrict__ Bb0, float* __restrict__ Bb1,
                       int* __restrict__ rowcnt) {
    int b = blockIdx.x, t = threadIdx.x; // 256
    if (b < PB_EMLP) {
        int gi = b >> 11;
        int e0 = (b & 2047) * 8;
        const float* ea = gi ? ea1 : ea0;
        float* hout = gi ? h1g : h0;
        __shared__ float h1s[8][HIDD];
#pragma unroll
        for (int r = 0; r < 4; ++r) {
            int idx = r * 256 + t;
            int e1 = idx >> 7, j = idx & 127;
            float acc = b1[j];
#pragma unroll
            for (int i = 0; i < FE; ++i) acc += ea[(e0 + e1) * FE + i] * w1[i * HIDD + j];
            h1s[e1][j] = fmaxf(acc, 0.f);
        }
        __syncthreads();
#pragma unroll
        for (int r = 0; r < 2; ++r) {
            int idx = r * 256 + t;
            int e1 = idx >> 6, j = idx & 63;
            float acc = b2[j];
#pragma unroll 16
            for (int k = 0; k < HIDD; ++k) acc += h1s[e1][k] * w2[k * 64 + j];
            hout[(size_t)(e0 + e1) * 64 + j] = fmaxf(acc, 0.f);
        }
    } else if (b < PB_BIAS) {
        int bb = b - PB_EMLP;         // 0..4095
        int gi = bb >> 11;
        int n = (bb & 2047) * 2 + (t >> 7);
        int o = t & 127;
        const float* X = gi ? X1 : X0;
        float* Bb = gi ? Bb1 : Bb0;
        float acc = 0.f;
#pragma unroll 16
        for (int i = 0; i < FIN; ++i) acc += X[n * FIN + i] * b3[i * HIDD + o];
        Bb[(size_t)n * HIDD + o] = acc;
    } else if (b < PB_HIST) {
        int tid = (b - PB_BIAS) * 256 + t; // 0..8191
        for (int idx = tid; idx < 2 * EP; idx += 32 * 256) {
            int gi = idx / EP, e = idx % EP;
            const int* dst = (gi ? ei1 : ei0) + NE;
            int d = (e < NE) ? dst[e] : e - NE;
            atomicAdd(&rowcnt[gi * NN + d], 1);
        }
    } else {
        // splitB: w3[c][i][o] -> f16 image B1t[c][o][i]
        __shared__ float lds[64 * 129];
        int c = b - PB_HIST;
#pragma unroll
        for (int r = 0; r < 32; ++r) {
            int idx = r * 256 + t;       // i = idx>>7, o = idx&127
            lds[(idx >> 7) * 129 + (idx & 127)] = w3[(size_t)c * 8192 + idx];
        }
        __syncthreads();
#pragma unroll
        for (int r = 0; r < 32; ++r) {
            int e = r * 256 + t;         // o = e>>6, i = e&63
            float v = lds[(e & 63) * 129 + (e >> 6)];
            union { _Float16 f; unsigned short u; } cv;
            cv.f = (_Float16)v;          // RNE
            B1t[(size_t)c * 8192 + e] = cv.u;
        }
    }
}

// ================= scan: rowptr per graph (shfl scan) + batch ranges =========
__global__ void k_scan(const int* __restrict__ rowcnt, int* __restrict__ rowptr,
                       const int* __restrict__ batch0, const int* __restrict__ batch1,
                       int* __restrict__ br) {
    int b = blockIdx.x;
    if (b < 2) {
        int gi = b;
        const int* cnt = rowcnt + gi * NN;
        int* rp = rowptr + gi * (NN + 1);
        int t = threadIdx.x; // 1024
        int lane = t & 63, w = t >> 6; // 16 waves
        int base = t * 4;
        int v0 = cnt[base], v1 = cnt[base + 1], v2 = cnt[base + 2], v3 = cnt[base + 3];
        int s = v0 + v1 + v2 + v3;
        int inc = s;
#pragma unroll
        for (int off = 1; off < 64; off <<= 1) {
            int u = __shfl_up(inc, off);
            if (lane >= off) inc += u;
        }
        __shared__ int wsum[16];
        if (lane == 63) wsum[w] = inc;
        __syncthreads();
        if (t < 16) {
            int ws = wsum[t];
            int wi = ws;
#pragma unroll
            for (int off = 1; off < 16; off <<= 1) {
                int u = __shfl_up(wi, off);
                if (t >= off) wi += u;
            }
            wsum[t] = wi - ws; // exclusive wave offset
        }
        __syncthreads();
        int run = wsum[w] + inc - s;
        rp[base] = run; run += v0;
        rp[base + 1] = run; run += v1;
        rp[base + 2] = run; run += v2;
        rp[base + 3] = run; run += v3;
        if (t == 1023) rp[NN] = run;
    } else {
        int t = threadIdx.x;
        if (t < 66) {
            int gi = t / 33, g = t % 33;
            const int* batch = gi ? batch1 : batch0;
            int lo = 0, hi = NN;
            while (lo < hi) {
                int mid = (lo + hi) >> 1;
                if (batch[mid] < g) lo = mid + 1; else hi = mid;
            }
            br[gi * 33 + g] = lo;
        }
    }
}

// ================= fill CSR adjacency =================
__global__ void k_fill(const int* __restrict__ ei0, const int* __restrict__ ei1,
                       const int* __restrict__ rowptr, int* __restrict__ cnt2,
                       int* __restrict__ adj) {
    int idx = blockIdx.x * 256 + threadIdx.x;
    if (idx >= 2 * EP) return;
    int gi = idx / EP, e = idx % EP;
    const int* dst = (gi ? ei1 : ei0) + NE;
    int d = (e < NE) ? dst[e] : e - NE;
    int pos = rowptr[gi * (NN + 1) + d] + atomicAdd(&cnt2[gi * NN + d], 1);
    adj[gi * EP + pos] = e;
}

// ===== NNConv message GEMM: r11 structure (best measured) + setprio =====
// block = 64 edges x 128 cols; 2 waves split cols; wave = 64 rows x 64 cols
__global__ void __launch_bounds__(128, 2)
k_nnconv(const float* __restrict__ x0, const float* __restrict__ x1,
         const float* __restrict__ h_0, const float* __restrict__ h_1,
         const unsigned short* __restrict__ B1t,
         const float* __restrict__ Bb0, const float* __restrict__ Bb1,
         const int* __restrict__ ei0, const int* __restrict__ ei1,
         _Float16* __restrict__ msgh) {
    __shared__ __align__(16) float sm[32 * 128]; // 16 KB epilogue bounce only
    int gi = blockIdx.z;
    const float* x = gi ? x1 : x0;
    const float* hh = gi ? h_1 : h_0;
    const float* Bb = gi ? Bb1 : Bb0;
    const int* src = gi ? ei1 : ei0;

    int t = threadIdx.x;       // 128
    int e0 = blockIdx.x * 64;
    int z = blockIdx.y;        // K-split half
    int ch = t >> 6;           // col half
    int l = t & 63, q4 = l >> 4, c16 = l & 15;

    // ---- prologue: load x rows, convert to f16 (RNE) fragments ----
    FragH xf[4][2];
#pragma unroll
    for (int mf = 0; mf < 4; ++mf) {
        int s_ = src[e0 + mf * 16 + c16];
        const float* xr = &x[(size_t)s_ * FIN];
#pragma unroll
        for (int kf = 0; kf < 2; ++kf) {
            float xv[8];
            *(float4*)&xv[0] = *(const float4*)&xr[kf * 32 + q4 * 8];
            *(float4*)&xv[4] = *(const float4*)&xr[kf * 32 + q4 * 8 + 4];
            u4v w;
#pragma unroll
            for (int p = 0; p < 4; ++p) {
                FH2 c2;
                c2.f[0] = (_Float16)xv[2 * p];
                c2.f[1] = (_Float16)xv[2 * p + 1];
                w[p] = c2.u;
            }
            xf[mf][kf].u = w;
        }
    }

    f4v acc[4][4];
#pragma unroll
    for (int a = 0; a < 4; ++a)
#pragma unroll
        for (int b = 0; b < 4; ++b) acc[a][b] = (f4v){0.f, 0.f, 0.f, 0.f};

    const u4v* bp = (const u4v*)B1t; // chunk = 1024 u4v

#define LOADF(buf, cg)                                                          \
    {                                                                           \
        const u4v* cp = bp + (size_t)(cg) * 1024;                               \
        _Pragma("unroll") for (int kf = 0; kf < 2; ++kf)                        \
        _Pragma("unroll") for (int nf = 0; nf < 4; ++nf)                        \
            buf[kf * 4 + nf].u = cp[(ch * 64 + nf * 16 + c16) * 8 + kf * 4 + q4]; \
    }

#define DOMFMA(buf, COMP)                                                       \
    {                                                                           \
        __builtin_amdgcn_s_setprio(1);                                          \
        _Pragma("unroll") for (int mf = 0; mf < 4; ++mf) {                      \
            FH2 hp2;                                                            \
            hp2.f[0] = (_Float16)hv4[mf].COMP;                                  \
            hp2.f[1] = hp2.f[0];                                                \
            unsigned hw = hp2.u;                                                \
            FragH hb; hb.u = (u4v){hw, hw, hw, hw};                             \
            _Pragma("unroll") for (int kf = 0; kf < 2; ++kf) {                  \
                FragH a1;                                                       \
                a1.h = hb.h * xf[mf][kf].h;                                     \
                _Pragma("unroll") for (int nf = 0; nf < 4; ++nf) {              \
                    acc[mf][nf] = __builtin_amdgcn_mfma_f32_16x16x32_f16(       \
                        a1.h, buf[kf * 4 + nf].h, acc[mf][nf], 0, 0, 0);        \
                }                                                               \
            }                                                                   \
        }                                                                       \
        __builtin_amdgcn_s_setprio(0);                                          \
    }

    FragH bA[8], bB[8];
    float4 hv4[4];
    LOADF(bA, z * NCH);
#pragma unroll 1
    for (int cl = 0; cl < NCH; cl += 4) {
#pragma unroll
        for (int mf = 0; mf < 4; ++mf)
            hv4[mf] = *(const float4*)&hh[(size_t)(e0 + mf * 16 + c16) * 64 + z * NCH + cl];
        LOADF(bB, z * NCH + cl + 1);
        DOMFMA(bA, x);
        LOADF(bA, z * NCH + cl + 2);
        DOMFMA(bB, y);
        LOADF(bB, z * NCH + cl + 3);
        DOMFMA(bA, z);
        if (cl + 4 < NCH) LOADF(bA, z * NCH + cl + 4);
        DOMFMA(bB, w);
    }
#undef LOADF
#undef DOMFMA

    // epilogue: bounce acc through LDS in two 32-row passes, f16 16B stores
    _Float16* mb = msgh + (size_t)(gi * KSPLIT + z) * NE * HIDD;
    int z0 = (z == 0);
#pragma unroll
    for (int half = 0; half < 2; ++half) {
        if (half) __syncthreads();  // WAR on sm
#pragma unroll
        for (int mf2 = 0; mf2 < 2; ++mf2) {
            int mf = half * 2 + mf2;
#pragma unroll
            for (int j = 0; j < 4; ++j) {
                int rr = mf2 * 16 + q4 * 4 + j;
#pragma unroll
                for (int nf = 0; nf < 4; ++nf)
                    sm[rr * 128 + ch * 64 + nf * 16 + c16] = acc[mf][nf][j];
            }
        }
        __syncthreads();
#pragma unroll
        for (int it = 0; it < 4; ++it) {
            int u = it * 128 + t;       // 0..511 units of 8 floats
            int row = u >> 4, c8 = u & 15;
            int eg = e0 + half * 32 + row;
            float v[8];
            *(float4*)&v[0] = *(float4*)&sm[row * 128 + c8 * 8];
            *(float4*)&v[4] = *(float4*)&sm[row * 128 + c8 * 8 + 4];
            if (z0) {
                int s_ = src[eg];
                const float* bbr = &Bb[(size_t)s_ * HIDD + c8 * 8];
#pragma unroll
                for (int j = 0; j < 8; ++j) v[j] += bbr[j];
            }
            F16x8U cv;
#pragma unroll
            for (int j = 0; j < 8; ++j) cv.f[j] = (_Float16)v[j];
            *(u4v*)&mb[(size_t)eg * HIDD + c8 * 8] = cv.u;
        }
    }
}

// ===== h1 = relu(gather(msg) + x@root_w + cb); hp = h1@gat_w; a_s,a_d =====
__global__ void k_h1hp(const _Float16* __restrict__ msgh,
                       const int* __restrict__ rowptr, const int* __restrict__ adj,
                       const float* __restrict__ X0, const float* __restrict__ X1,
                       const float* __restrict__ rw, const float* __restrict__ cb,
                       const float* __restrict__ gw,
                       const float* __restrict__ asw, const float* __restrict__ adw,
                       float* __restrict__ hp0, float* __restrict__ hp1,
                       float* __restrict__ a_s0, float* __restrict__ a_s1,
                       float* __restrict__ a_d0, float* __restrict__ a_d1) {
    int gi = blockIdx.y;
    const float* X = gi ? X1 : X0;
    float* hp = gi ? hp1 : hp0;
    float* a_s = gi ? a_s1 : a_s0;
    float* a_d = gi ? a_d1 : a_d0;
    const int* rp = rowptr + gi * (NN + 1);
    const int* aj = adj + gi * EP;
    const _Float16* m0 = msgh + (size_t)(gi * KSPLIT + 0) * NE * HIDD;
    const _Float16* m1 = msgh + (size_t)(gi * KSPLIT + 1) * NE * HIDD;
    int n0 = blockIdx.x * 16;
    int t = threadIdx.x;        // 512
    int o = t & 127, q = t >> 7;
    __shared__ float xsh[16][FIN];
    __shared__ float h1s[16][HIDD];
    __shared__ float s1[16][2], s2[16][2];
#pragma unroll
    for (int r = 0; r < 2; ++r) {
        int idx = r * 512 + t;
        xsh[idx >> 6][idx & 63] = X[(n0 + (idx >> 6)) * FIN + (idx & 63)];
    }
    __syncthreads();
    float accs[4];
#pragma unroll
    for (int nn = 0; nn < 4; ++nn) {
        int n = n0 + q * 4 + nn;
        float acc = cb[o];
        int lo = rp[n], hi = rp[n + 1];
        for (int p = lo; p < hi; ++p) {
            int e = aj[p];
            if (e < NE) {
                size_t eo = (size_t)e * HIDD + o;
                acc += (float)m0[eo] + (float)m1[eo];
            }
        }
        accs[nn] = acc;
    }
#pragma unroll 8
    for (int i = 0; i < FIN; ++i) {
        float w = rw[i * HIDD + o];
#pragma unroll
        for (int nn = 0; nn < 4; ++nn) accs[nn] += xsh[q * 4 + nn][i] * w;
    }
#pragma unroll
    for (int nn = 0; nn < 4; ++nn) h1s[q * 4 + nn][o] = fmaxf(accs[nn], 0.f);
    __syncthreads();
#pragma unroll
    for (int nn = 0; nn < 4; ++nn) accs[nn] = 0.f;
#pragma unroll 8
    for (int k = 0; k < HIDD; ++k) {
        float w = gw[k * HIDD + o];
#pragma unroll
        for (int nn = 0; nn < 4; ++nn) accs[nn] += h1s[q * 4 + nn][k] * w;
    }
#pragma unroll
    for (int nn = 0; nn < 4; ++nn) {
        int n = n0 + q * 4 + nn;
        hp[(size_t)n * HIDD + o] = accs[nn];
        float p1 = accs[nn] * asw[o], p2 = accs[nn] * adw[o];
#pragma unroll
        for (int off = 32; off; off >>= 1) {
            p1 += __shfl_down(p1, off);
            p2 += __shfl_down(p2, off);
        }
        if ((o & 63) == 0) { s1[q * 4 + nn][o >> 6] = p1; s2[q * 4 + nn][o >> 6] = p2; }
    }
    __syncthreads();
    if (t < 16) {
        a_s[n0 + t] = s1[t][0] + s1[t][1];
        a_d[n0 + t] = s2[t][0] + s2[t][1];
    }
}

// ===== GAT: wave per dst node =====
__global__ void k_gat(const int* __restrict__ rowptr, const int* __restrict__ adj,
                      const int* __restrict__ ei0, const int* __restrict__ ei1,
                      const float* __restrict__ hp0, const float* __restrict__ hp1,
                      const float* __restrict__ as0, const float* __restrict__ as1,
                      const float* __restrict__ ad0, const float* __restrict__ ad1,
                      const float* __restrict__ gb,
                      float* __restrict__ h2_0, float* __restrict__ h2_1) {
    int gi = blockIdx.y;
    const int* src = gi ? ei1 : ei0;
    const float* hp = gi ? hp1 : hp0;
    const float* a_s = gi ? as1 : as0;
    const float* a_d = gi ? ad1 : ad0;
    float* h2 = gi ? h2_1 : h2_0;
    const int* rp = rowptr + gi * (NN + 1);
    const int* aj = adj + gi * EP;
    int w = threadIdx.x >> 6, l = threadIdx.x & 63;
    int n = blockIdx.x * 4 + w;
    int lo = rp[n], deg = rp[n + 1] - lo;
    float adn = a_d[n];
    float m = -1e30f;
    for (int base = 0; base < deg; base += 64) {
        float sc = -1e30f;
        int j = base + l;
        if (j < deg) {
            int e = aj[lo + j];
            int si = (e < NE) ? src[e] : n;
            float xsc = a_s[si] + adn;
            sc = xsc > 0.f ? xsc : 0.2f * xsc;
        }
#pragma unroll
        for (int off = 32; off; off >>= 1) sc = fmaxf(sc, __shfl_xor(sc, off));
        m = fmaxf(m, sc);
    }
    float den = 0.f;
    for (int base = 0; base < deg; base += 64) {
        float ev = 0.f;
        int j = base + l;
        if (j < deg) {
            int e = aj[lo + j];
            int si = (e < NE) ? src[e] : n;
            float xsc = a_s[si] + adn;
            float sc = xsc > 0.f ? xsc : 0.2f * xsc;
            ev = expf(sc - m);
        }
#pragma unroll
        for (int off = 32; off; off >>= 1) ev += __shfl_xor(ev, off);
        den += ev;
    }
    float inv = 1.f / (den + 1e-16f);
    float acc0 = 0.f, acc1 = 0.f;
    for (int j = 0; j < deg; ++j) {
        int e = aj[lo + j];
        int si = (e < NE) ? src[e] : n;
        float xsc = a_s[si] + adn;
        float sc = xsc > 0.f ? xsc : 0.2f * xsc;
        float al = expf(sc - m) * inv;
        acc0 += al * hp[(size_t)si * HIDD + l];
        acc1 += al * hp[(size_t)si * HIDD + 64 + l];
    }
    h2[(size_t)n * HIDD + l] = fmaxf(acc0 + gb[l], 0.f);
    h2[(size_t)n * HIDD + 64 + l] = fmaxf(acc1 + gb[64 + l], 0.f);
}

// ===== mean-pool (batch ranges) + fc1 =====
__global__ void k_poolfc1(const float* __restrict__ h2_0, const float* __restrict__ h2_1,
                          const int* __restrict__ br,
                          const float* __restrict__ w, const float* __restrict__ bias,
                          float* __restrict__ z) {
    int gi = blockIdx.x >> 5, g = blockIdx.x & 31;
    const float* h2 = gi ? h2_1 : h2_0;
    int lo = br[gi * 33 + g], hi = br[gi * 33 + g + 1];
    int t = threadIdx.x; // 128
    __shared__ float pool[HIDD];
    float acc = 0.f;
    for (int n = lo; n < hi; ++n) acc += h2[(size_t)n * HIDD + t];
    pool[t] = acc;
    __syncthreads();
    if (t < 64) {
        float c = fmaxf((float)(hi - lo), 1.f);
        float a = bias[t];
#pragma unroll 16
        for (int o = 0; o < HIDD; ++o) a += (pool[o] / c) * w[o * OUTD + t];
        z[gi * NG * OUTD + g * OUTD + t] = fmaxf(a, 0.f);
    }
}

// ===== final =====
__global__ void k_final(const float* __restrict__ zz,
                        const float* __restrict__ w, const float* __restrict__ b,
                        float* __restrict__ out) {
    int g = threadIdx.x; // 32
    const float* z1 = zz;
    const float* z2 = zz + NG * OUTD;
    float acc = b[0];
#pragma unroll
    for (int j = 0; j < OUTD; ++j) acc += fabsf(z1[g * OUTD + j] - z2[g * OUTD + j]) * w[j];
    out[g] = 1.f / (1.f + expf(-acc));
}

extern "C" void kernel_launch(void* const* d_in, const int* in_sizes, int n_in,
                              void* d_out, int out_size, void* d_ws, size_t ws_size,
                              hipStream_t stream) {
    const float* x0     = (const float*)d_in[0];
    const int*   ei0    = (const int*)d_in[1];
    const float* ea0    = (const float*)d_in[2];
    const int*   b0     = (const int*)d_in[3];
    const float* x1     = (const float*)d_in[4];
    const int*   ei1    = (const int*)d_in[5];
    const float* ea1    = (const float*)d_in[6];
    const int*   b1     = (const int*)d_in[7];
    const float* e_w1 = (const float*)d_in[8];
    const float* e_b1 = (const float*)d_in[9];
    const float* e_w2 = (const float*)d_in[10];
    const float* e_b2 = (const float*)d_in[11];
    const float* e_w3 = (const float*)d_in[12];
    const float* e_b3 = (const float*)d_in[13];
    const float* root_w = (const float*)d_in[14];
    const float* conv1_b = (const float*)d_in[15];
    const float* gat_w = (const float*)d_in[16];
    const float* att_src = (const float*)d_in[17];
    const float* att_dst = (const float*)d_in[18];
    const float* gat_b = (const float*)d_in[19];
    const float* fc1_w = (const float*)d_in[20];
    const float* fc1_b = (const float*)d_in[21];
    const float* fc2_w = (const float*)d_in[22];
    const float* fc2_b = (const float*)d_in[23];

    float* ws = (float*)d_ws;
    size_t off = 0;
    auto alloc = [&](size_t n) { float* p = ws + off; off += n; return p; };
    // int region (zeroed part first)
    int* rowcnt = (int*)alloc(2 * NN);
    int* cnt2   = (int*)alloc(2 * NN);
    size_t zero_elems = off;
    int* rowptr = (int*)alloc(2 * (NN + 1));
    int* br     = (int*)alloc(66);
    int* adj    = (int*)alloc(2 * EP);
    // float scratch
    float* h[2]   = {alloc((size_t)NE * 64), alloc((size_t)NE * 64)};
    unsigned short* B1t = (unsigned short*)alloc((size_t)4096 * 128 / 2); // 1MB f16 image
    float* Bb[2]  = {alloc((size_t)NN * HIDD), alloc((size_t)NN * HIDD)};
    _Float16* msgh = (_Float16*)alloc((size_t)2 * KSPLIT * NE * HIDD / 2); // 16.7MB f16
    float* hp[2]  = {alloc((size_t)NN * HIDD), alloc((size_t)NN * HIDD)};
    float* a_s[2] = {alloc(NN), alloc(NN)};
    float* a_d[2] = {alloc(NN), alloc(NN)};
    float* h2[2]  = {alloc((size_t)NN * HIDD), alloc((size_t)NN * HIDD)};
    float* zz     = alloc((size_t)2 * NG * OUTD);

    (void)hipMemsetAsync(ws, 0, zero_elems * 4, stream);
    k_prep<<<PB_TOTAL, 256, 0, stream>>>(ea0, ea1, e_w1, e_b1, e_w2, e_b2, e_w3,
                                         x0, x1, e_b3, ei0, ei1,
                                         B1t, h[0], h[1], Bb[0], Bb[1],
                                         rowcnt);
    k_scan<<<3, 1024, 0, stream>>>(rowcnt, rowptr, b0, b1, br);
    k_fill<<<(2 * EP + 255) / 256, 256, 0, stream>>>(ei0, ei1, rowptr, cnt2, adj);
    k_nnconv<<<dim3(NE / 64, KSPLIT, 2), 128, 0, stream>>>(
        x0, x1, h[0], h[1], B1t, Bb[0], Bb[1], ei0, ei1, msgh);
    k_h1hp<<<dim3(NN / 16, 2), 512, 0, stream>>>(
        msgh, rowptr, adj, x0, x1, root_w, conv1_b, gat_w, att_src, att_dst,
        hp[0], hp[1], a_s[0], a_s[1], a_d[0], a_d[1]);
    k_gat<<<dim3(NN / 4, 2), 256, 0, stream>>>(
        rowptr, adj, ei0, ei1, hp[0], hp[1], a_s[0], a_s[1], a_d[0], a_d[1],
        gat_b, h2[0], h2[1]);
    k_poolfc1<<<64, HIDD, 0, stream>>>(h2[0], h2[1], br, fc1_w, fc1_b, zz);
    k_final<<<1, NG, 0, stream>>>(zz, fc2_w, fc2_b, (float*)d_out);
}